// Round 1
// baseline (951.799 us; speedup 1.0000x reference)
//
#include <hip/hip_runtime.h>
#include <stdint.h>

#define DIMSZ 2048
#define HD 128
#define NH 16
#define BATCH 2
#define SEQ 2048
#define MROWS (BATCH*SEQ)   // 4096
#define FFDIM (4*DIMSZ)     // 8192

typedef float f32x4 __attribute__((ext_vector_type(4)));
typedef __bf16 bf16x8 __attribute__((ext_vector_type(8)));
typedef __bf16 bf16_t;

__device__ __forceinline__ void async16(const void* g, void* l) {
  __builtin_amdgcn_global_load_lds(
      (const __attribute__((address_space(1))) void*)(uintptr_t)g,
      (__attribute__((address_space(3))) void*)(uint32_t)(uintptr_t)l,
      16, 0, 0);
}

__device__ __forceinline__ float gelu_f(float x) {
  return 0.5f * x * (1.0f + erff(x * 0.70710678118654752f));
}

// ---------------- transpose f32 (R x C) -> bf16 (C x R) ----------------
__global__ __launch_bounds__(256)
void k_transpose_f32_bf16(const float* __restrict__ src, bf16_t* __restrict__ dst,
                          int R, int C) {
  __shared__ float tile[32][33];
  int c0 = blockIdx.x * 32, r0 = blockIdx.y * 32;
  int tx = threadIdx.x & 31, ty = threadIdx.x >> 5;
#pragma unroll
  for (int i = 0; i < 32; i += 8)
    tile[ty + i][tx] = src[(size_t)(r0 + ty + i) * C + (c0 + tx)];
  __syncthreads();
#pragma unroll
  for (int i = 0; i < 32; i += 8)
    dst[(size_t)(c0 + ty + i) * R + (r0 + tx)] = (bf16_t)tile[tx][ty + i];
}

// ---------------- transpose v bf16 [B*T][128] -> vt [B][128][T] ----------------
__global__ __launch_bounds__(256)
void k_transpose_v(const bf16_t* __restrict__ v, bf16_t* __restrict__ vt) {
  __shared__ bf16_t tile[32][33];
  int b = blockIdx.z;
  int t0 = blockIdx.x * 32, d0 = blockIdx.y * 32;
  int tx = threadIdx.x & 31, ty = threadIdx.x >> 5;
#pragma unroll
  for (int i = 0; i < 32; i += 8)
    tile[ty + i][tx] = v[((size_t)(b * SEQ + t0 + ty + i)) * HD + d0 + tx];
  __syncthreads();
#pragma unroll
  for (int i = 0; i < 32; i += 8)
    vt[((size_t)(b * HD + d0 + ty + i)) * SEQ + t0 + tx] = tile[tx][ty + i];
}

// ---------------- layernorm f32 -> bf16 ----------------
__global__ __launch_bounds__(256)
void k_layernorm(const float* __restrict__ x, const float* __restrict__ g,
                 const float* __restrict__ bb, bf16_t* __restrict__ out) {
  int row = blockIdx.x;
  const float* xr = x + (size_t)row * DIMSZ;
  int t = threadIdx.x;
  float vals[8];
  float s = 0.f, s2 = 0.f;
#pragma unroll
  for (int i = 0; i < 8; ++i) {
    float v = xr[t + i * 256];
    vals[i] = v; s += v; s2 += v * v;
  }
#pragma unroll
  for (int o = 1; o < 64; o <<= 1) { s += __shfl_xor(s, o); s2 += __shfl_xor(s2, o); }
  __shared__ float red[8];
  if ((t & 63) == 0) { red[t >> 6] = s; red[4 + (t >> 6)] = s2; }
  __syncthreads();
  s = red[0] + red[1] + red[2] + red[3];
  s2 = red[4] + red[5] + red[6] + red[7];
  float mu = s * (1.0f / DIMSZ);
  float rstd = rsqrtf(s2 * (1.0f / DIMSZ) - mu * mu + 1e-5f);
  bf16_t* orow = out + (size_t)row * DIMSZ;
#pragma unroll
  for (int i = 0; i < 8; ++i) {
    int c = t + i * 256;
    orow[c] = (bf16_t)((vals[i] - mu) * rstd * g[c] + bb[c]);
  }
}

// ---------------- bf16 GEMM: C[M,N] = A[M,K] * BT[N,K]^T + bias (+epilogue) ----
// EPI bits: 1 = exact GELU, 2 = add residual f32, 4 = write f32, 8 = write bf16
template <int EPI>
__global__ __launch_bounds__(256, 2)
void k_gemm(const bf16_t* __restrict__ A, const bf16_t* __restrict__ BT,
            const float* __restrict__ bias, const float* res,
            float* outF, bf16_t* outB, int M, int N, int K) {
  __shared__ __align__(16) bf16_t As[128 * 64];
  __shared__ __align__(16) bf16_t Bs[128 * 64];
  int nt = N >> 7;
  int bm = blockIdx.x / nt, bn = blockIdx.x % nt;
  int tid = threadIdx.x;
  int wave = tid >> 6, lane = tid & 63, lr = lane & 15, lg = lane >> 4;
  int wm = (wave >> 1) << 6, wn = (wave & 1) << 6;
  const bf16_t* Ab = A + (size_t)bm * 128 * K;
  const bf16_t* Bb = BT + (size_t)bn * 128 * K;
  f32x4 acc[4][4] = {};
  for (int k0 = 0; k0 < K; k0 += 64) {
    __syncthreads();
#pragma unroll
    for (int i = 0; i < 4; ++i) {
      int flat = (i * 256 + tid) * 8;
      int r = flat >> 6, c = flat & 63;
      async16(Ab + (size_t)r * K + k0 + c, (void*)(As + flat));
      async16(Bb + (size_t)r * K + k0 + c, (void*)(Bs + flat));
    }
    __syncthreads();
#pragma unroll
    for (int kk = 0; kk < 64; kk += 32) {
      bf16x8 af[4], bfr[4];
#pragma unroll
      for (int mf = 0; mf < 4; ++mf)
        af[mf] = *(const bf16x8*)(As + (wm + mf * 16 + lr) * 64 + kk + lg * 8);
#pragma unroll
      for (int nf = 0; nf < 4; ++nf)
        bfr[nf] = *(const bf16x8*)(Bs + (wn + nf * 16 + lr) * 64 + kk + lg * 8);
#pragma unroll
      for (int mf = 0; mf < 4; ++mf)
#pragma unroll
        for (int nf = 0; nf < 4; ++nf)
          acc[mf][nf] = __builtin_amdgcn_mfma_f32_16x16x32_bf16(af[mf], bfr[nf], acc[mf][nf], 0, 0, 0);
    }
  }
  int row0 = bm * 128 + wm + lg * 4;
  int col0 = bn * 128 + wn + lr;
#pragma unroll
  for (int nf = 0; nf < 4; ++nf) {
    int c = col0 + nf * 16;
    float bi = bias[c];
#pragma unroll
    for (int mf = 0; mf < 4; ++mf) {
#pragma unroll
      for (int j = 0; j < 4; ++j) {
        int r = row0 + mf * 16 + j;
        size_t idx = (size_t)r * N + c;
        float v = acc[mf][nf][j] + bi;
        if (EPI & 1) v = gelu_f(v);
        if (EPI & 2) v += res[idx];
        if (EPI & 4) outF[idx] = v;
        if (EPI & 8) outB[idx] = (bf16_t)v;
      }
    }
  }
}

// ---------------- causal flash attention (MQA), 1 block = (b, h, 64 q-rows) ----
__global__ __launch_bounds__(256, 2)
void k_attn(const bf16_t* __restrict__ q, const bf16_t* __restrict__ k,
            const bf16_t* __restrict__ vt, bf16_t* __restrict__ ctx) {
  __shared__ __align__(16) bf16_t Ks[64 * 128];
  __shared__ __align__(16) bf16_t Vt[128 * 64];
  __shared__ __align__(16) bf16_t Pw[4][16 * 64];
  int qt = blockIdx.x, h = blockIdx.y, b = blockIdx.z;
  int tid = threadIdx.x, wave = tid >> 6, lane = tid & 63, lr = lane & 15, lg = lane >> 4;
  int q0 = qt * 64;
  int qw = q0 + wave * 16;
  const bf16_t* qbase = q + ((size_t)(b * SEQ + qw + lr)) * DIMSZ + h * HD;
  bf16x8 qf[4];
#pragma unroll
  for (int kk = 0; kk < 4; ++kk) qf[kk] = *(const bf16x8*)(qbase + kk * 32 + lg * 8);
  f32x4 o[8] = {};
  float m_[4], l_[4];
#pragma unroll
  for (int j = 0; j < 4; ++j) { m_[j] = -3.0e38f; l_[j] = 0.f; }
  const bf16_t* kb = k + (size_t)b * SEQ * HD;
  const bf16_t* vb = vt + (size_t)b * HD * SEQ;
  int qglob0 = qw + lg * 4;
  for (int s0 = 0; s0 < q0 + 64; s0 += 64) {
    __syncthreads();
#pragma unroll
    for (int i = 0; i < 4; ++i) {
      int flat = (i * 256 + tid) * 8;
      int r = flat >> 7, c = flat & 127;
      async16(kb + (size_t)(s0 + r) * HD + c, (void*)(Ks + flat));
      int d = flat >> 6, c2 = flat & 63;
      async16(vb + (size_t)d * SEQ + s0 + c2, (void*)(Vt + flat));
    }
    __syncthreads();
    f32x4 sf[4] = {};
#pragma unroll
    for (int nf = 0; nf < 4; ++nf)
#pragma unroll
      for (int kk = 0; kk < 4; ++kk)
        sf[nf] = __builtin_amdgcn_mfma_f32_16x16x32_bf16(
            qf[kk], *(const bf16x8*)(Ks + (nf * 16 + lr) * 128 + kk * 32 + lg * 8), sf[nf], 0, 0, 0);
#pragma unroll
    for (int nf = 0; nf < 4; ++nf) {
      int col = s0 + nf * 16 + lr;
#pragma unroll
      for (int j = 0; j < 4; ++j) {
        float v = sf[nf][j] * 0.088388347648318447f;
        sf[nf][j] = (col <= qglob0 + j) ? v : -3.0e38f;
      }
    }
    float mx[4];
#pragma unroll
    for (int j = 0; j < 4; ++j)
      mx[j] = fmaxf(fmaxf(sf[0][j], sf[1][j]), fmaxf(sf[2][j], sf[3][j]));
#pragma unroll
    for (int o_ = 1; o_ < 16; o_ <<= 1)
#pragma unroll
      for (int j = 0; j < 4; ++j) mx[j] = fmaxf(mx[j], __shfl_xor(mx[j], o_));
    float fsc[4], mn[4];
#pragma unroll
    for (int j = 0; j < 4; ++j) {
      mn[j] = fmaxf(m_[j], mx[j]);
      fsc[j] = __expf(m_[j] - mn[j]);
      m_[j] = mn[j];
    }
    float ps[4] = {0.f, 0.f, 0.f, 0.f};
#pragma unroll
    for (int nf = 0; nf < 4; ++nf)
#pragma unroll
      for (int j = 0; j < 4; ++j) {
        float p = __expf(sf[nf][j] - mn[j]);
        ps[j] += p;
        Pw[wave][(lg * 4 + j) * 64 + nf * 16 + lr] = (bf16_t)p;
      }
#pragma unroll
    for (int o_ = 1; o_ < 16; o_ <<= 1)
#pragma unroll
      for (int j = 0; j < 4; ++j) ps[j] += __shfl_xor(ps[j], o_);
#pragma unroll
    for (int j = 0; j < 4; ++j) l_[j] = l_[j] * fsc[j] + ps[j];
#pragma unroll
    for (int df = 0; df < 8; ++df)
#pragma unroll
      for (int j = 0; j < 4; ++j) o[df][j] *= fsc[j];
    asm volatile("" ::: "memory");  // keep compiler from reordering LDS read before writes
    bf16x8 pa[2];
#pragma unroll
    for (int kk = 0; kk < 2; ++kk)
      pa[kk] = *(const bf16x8*)(&Pw[wave][lr * 64 + kk * 32 + lg * 8]);
#pragma unroll
    for (int df = 0; df < 8; ++df)
#pragma unroll
      for (int kk = 0; kk < 2; ++kk)
        o[df] = __builtin_amdgcn_mfma_f32_16x16x32_bf16(
            pa[kk], *(const bf16x8*)(Vt + (df * 16 + lr) * 64 + kk * 32 + lg * 8), o[df], 0, 0, 0);
  }
  bf16_t* cb = ctx + ((size_t)(b * SEQ + qw)) * DIMSZ + h * HD;
#pragma unroll
  for (int df = 0; df < 8; ++df)
#pragma unroll
    for (int j = 0; j < 4; ++j)
      cb[(size_t)(lg * 4 + j) * DIMSZ + df * 16 + lr] = (bf16_t)(o[df][j] / l_[j]);
}

extern "C" void kernel_launch(void* const* d_in, const int* in_sizes, int n_in,
                              void* d_out, int out_size, void* d_ws, size_t ws_size,
                              hipStream_t stream) {
  const float* x   = (const float*)d_in[0];
  const float* wq  = (const float*)d_in[2];
  const float* bq  = (const float*)d_in[3];
  const float* wk  = (const float*)d_in[4];
  const float* bk  = (const float*)d_in[5];
  const float* wv  = (const float*)d_in[6];
  const float* bv  = (const float*)d_in[7];
  const float* wo  = (const float*)d_in[8];
  const float* bo  = (const float*)d_in[9];
  const float* g1  = (const float*)d_in[10];
  const float* be1 = (const float*)d_in[11];
  const float* g2  = (const float*)d_in[12];
  const float* be2 = (const float*)d_in[13];
  const float* w1  = (const float*)d_in[14];
  const float* bb1 = (const float*)d_in[15];
  const float* w2  = (const float*)d_in[16];
  const float* bb2 = (const float*)d_in[17];

  float* outx = (float*)d_out;                       // [4096][2048] (also x1 scratch)
  float* outk = outx + (size_t)MROWS * DIMSZ;        // [4096][128]
  float* outv = outk + (size_t)MROWS * HD;           // [4096][128]

  char* p = (char*)d_ws;
  auto alloc = [&](size_t bytes) -> char* {
    char* r = p;
    p += (bytes + 255) & ~(size_t)255;
    return r;
  };
  bf16_t* wqT = (bf16_t*)alloc((size_t)DIMSZ * DIMSZ * 2);
  bf16_t* wkT = (bf16_t*)alloc((size_t)HD * DIMSZ * 2);
  bf16_t* wvT = (bf16_t*)alloc((size_t)HD * DIMSZ * 2);
  bf16_t* woT = (bf16_t*)alloc((size_t)DIMSZ * DIMSZ * 2);
  bf16_t* w1T = (bf16_t*)alloc((size_t)FFDIM * DIMSZ * 2);
  bf16_t* w2T = (bf16_t*)alloc((size_t)DIMSZ * FFDIM * 2);
  bf16_t* hb  = (bf16_t*)alloc((size_t)MROWS * DIMSZ * 2);  // h, later ctx
  bf16_t* qb  = (bf16_t*)alloc((size_t)MROWS * DIMSZ * 2);  // q, later h2
  bf16_t* kbf = (bf16_t*)alloc((size_t)MROWS * HD * 2);
  bf16_t* vbf = (bf16_t*)alloc((size_t)MROWS * HD * 2);
  bf16_t* vtb = (bf16_t*)alloc((size_t)BATCH * HD * SEQ * 2);
  bf16_t* f1b = (bf16_t*)alloc((size_t)MROWS * FFDIM * 2);
  (void)ws_size; (void)in_sizes; (void)n_in; (void)out_size;

  dim3 blk(256);
  // weight transposes / bf16 conversion
  k_transpose_f32_bf16<<<dim3(DIMSZ / 32, DIMSZ / 32), blk, 0, stream>>>(wq, wqT, DIMSZ, DIMSZ);
  k_transpose_f32_bf16<<<dim3(HD / 32, DIMSZ / 32), blk, 0, stream>>>(wk, wkT, DIMSZ, HD);
  k_transpose_f32_bf16<<<dim3(HD / 32, DIMSZ / 32), blk, 0, stream>>>(wv, wvT, DIMSZ, HD);
  k_transpose_f32_bf16<<<dim3(DIMSZ / 32, DIMSZ / 32), blk, 0, stream>>>(wo, woT, DIMSZ, DIMSZ);
  k_transpose_f32_bf16<<<dim3(FFDIM / 32, DIMSZ / 32), blk, 0, stream>>>(w1, w1T, DIMSZ, FFDIM);
  k_transpose_f32_bf16<<<dim3(DIMSZ / 32, FFDIM / 32), blk, 0, stream>>>(w2, w2T, FFDIM, DIMSZ);
  // ln1: x -> h(bf16)
  k_layernorm<<<MROWS, blk, 0, stream>>>(x, g1, be1, hb);
  // q,k,v projections
  k_gemm<8><<<(MROWS / 128) * (DIMSZ / 128), blk, 0, stream>>>(hb, wqT, bq, nullptr, nullptr, qb, MROWS, DIMSZ, DIMSZ);
  k_gemm<12><<<(MROWS / 128) * (HD / 128), blk, 0, stream>>>(hb, wkT, bk, nullptr, outk, kbf, MROWS, HD, DIMSZ);
  k_gemm<12><<<(MROWS / 128) * (HD / 128), blk, 0, stream>>>(hb, wvT, bv, nullptr, outv, vbf, MROWS, HD, DIMSZ);
  k_transpose_v<<<dim3(SEQ / 32, HD / 32, BATCH), blk, 0, stream>>>(vbf, vtb);
  // attention -> ctx (reuse hb)
  k_attn<<<dim3(SEQ / 64, NH, BATCH), blk, 0, stream>>>(qb, kbf, vtb, hb);
  // o-proj + residual -> outx (x1)
  k_gemm<6><<<(MROWS / 128) * (DIMSZ / 128), blk, 0, stream>>>(hb, woT, bo, x, outx, nullptr, MROWS, DIMSZ, DIMSZ);
  // ln2: x1 -> h2 (reuse qb)
  k_layernorm<<<MROWS, blk, 0, stream>>>(outx, g2, be2, qb);
  // ffn1 + exact gelu -> f1b (bf16)
  k_gemm<9><<<(MROWS / 128) * (FFDIM / 128), blk, 0, stream>>>(qb, w1T, bb1, nullptr, nullptr, f1b, MROWS, FFDIM, DIMSZ);
  // ffn2 + residual -> outx (final x)
  k_gemm<6><<<(MROWS / 128) * (DIMSZ / 128), blk, 0, stream>>>(f1b, w2T, bb2, outx, outx, nullptr, MROWS, DIMSZ, FFDIM);
}

// Round 2
// 899.993 us; speedup vs baseline: 1.0576x; 1.0576x over previous
//
#include <hip/hip_runtime.h>
#include <stdint.h>

#define DIMSZ 2048
#define HD 128
#define NH 16
#define BATCH 2
#define SEQ 2048
#define MROWS (BATCH*SEQ)   // 4096
#define FFDIM (4*DIMSZ)     // 8192
#define NQKV (DIMSZ + 2*HD) // 2304

typedef float f32x4 __attribute__((ext_vector_type(4)));
typedef __bf16 bf16x8 __attribute__((ext_vector_type(8)));
typedef __bf16 bf16_t;

__device__ __forceinline__ void async16(const void* g, void* l) {
  __builtin_amdgcn_global_load_lds(
      (const __attribute__((address_space(1))) void*)(uintptr_t)g,
      (__attribute__((address_space(3))) void*)(uint32_t)(uintptr_t)l,
      16, 0, 0);
}

__device__ __forceinline__ float gelu_f(float x) {
  return 0.5f * x * (1.0f + erff(x * 0.70710678118654752f));
}

// ---------------- transpose f32 (R x C) -> bf16 (C x R) ----------------
__global__ __launch_bounds__(256)
void k_transpose_f32_bf16(const float* __restrict__ src, bf16_t* __restrict__ dst,
                          int R, int C) {
  __shared__ float tile[32][33];
  int c0 = blockIdx.x * 32, r0 = blockIdx.y * 32;
  int tx = threadIdx.x & 31, ty = threadIdx.x >> 5;
#pragma unroll
  for (int i = 0; i < 32; i += 8)
    tile[ty + i][tx] = src[(size_t)(r0 + ty + i) * C + (c0 + tx)];
  __syncthreads();
#pragma unroll
  for (int i = 0; i < 32; i += 8)
    dst[(size_t)(c0 + ty + i) * R + (r0 + tx)] = (bf16_t)tile[tx][ty + i];
}

// ---------------- transpose v bf16 [B*T][128] -> vt [B][128][T] ----------------
__global__ __launch_bounds__(256)
void k_transpose_v(const bf16_t* __restrict__ v, bf16_t* __restrict__ vt) {
  __shared__ bf16_t tile[32][33];
  int b = blockIdx.z;
  int t0 = blockIdx.x * 32, d0 = blockIdx.y * 32;
  int tx = threadIdx.x & 31, ty = threadIdx.x >> 5;
#pragma unroll
  for (int i = 0; i < 32; i += 8)
    tile[ty + i][tx] = v[((size_t)(b * SEQ + t0 + ty + i)) * HD + d0 + tx];
  __syncthreads();
#pragma unroll
  for (int i = 0; i < 32; i += 8)
    vt[((size_t)(b * HD + d0 + ty + i)) * SEQ + t0 + tx] = tile[tx][ty + i];
}

// ---------------- layernorm f32 -> bf16 ----------------
__global__ __launch_bounds__(256)
void k_layernorm(const float* __restrict__ x, const float* __restrict__ g,
                 const float* __restrict__ bb, bf16_t* __restrict__ out) {
  int row = blockIdx.x;
  const float* xr = x + (size_t)row * DIMSZ;
  int t = threadIdx.x;
  float vals[8];
  float s = 0.f, s2 = 0.f;
#pragma unroll
  for (int i = 0; i < 8; ++i) {
    float v = xr[t + i * 256];
    vals[i] = v; s += v; s2 += v * v;
  }
#pragma unroll
  for (int o = 1; o < 64; o <<= 1) { s += __shfl_xor(s, o); s2 += __shfl_xor(s2, o); }
  __shared__ float red[8];
  if ((t & 63) == 0) { red[t >> 6] = s; red[4 + (t >> 6)] = s2; }
  __syncthreads();
  s = red[0] + red[1] + red[2] + red[3];
  s2 = red[4] + red[5] + red[6] + red[7];
  float mu = s * (1.0f / DIMSZ);
  float rstd = rsqrtf(s2 * (1.0f / DIMSZ) - mu * mu + 1e-5f);
  bf16_t* orow = out + (size_t)row * DIMSZ;
#pragma unroll
  for (int i = 0; i < 8; ++i) {
    int c = t + i * 256;
    orow[c] = (bf16_t)((vals[i] - mu) * rstd * g[c] + bb[c]);
  }
}

// ---------------- GEMM main loop (shared by both GEMM kernels) ----------------
// Computes 128x128 C-tile: acc[4][4] per wave (2x2 wave grid, 64x64 each).
#define GEMM_MAINLOOP(Ab, Bb, K)                                                  \
  f32x4 acc[4][4] = {};                                                           \
  for (int k0 = 0; k0 < (K); k0 += 64) {                                          \
    __syncthreads();                                                              \
    _Pragma("unroll")                                                             \
    for (int i = 0; i < 4; ++i) {                                                 \
      int flat = (i * 256 + tid) * 8;                                             \
      int r = flat >> 6, c = flat & 63;                                           \
      async16((Ab) + (size_t)r * (K) + k0 + c, (void*)(As + flat));               \
      async16((Bb) + (size_t)r * (K) + k0 + c, (void*)(Bs + flat));               \
    }                                                                             \
    __syncthreads();                                                              \
    _Pragma("unroll")                                                             \
    for (int kk = 0; kk < 64; kk += 32) {                                         \
      bf16x8 af[4], bfr[4];                                                       \
      _Pragma("unroll")                                                           \
      for (int mf = 0; mf < 4; ++mf)                                              \
        af[mf] = *(const bf16x8*)(As + (wm + mf * 16 + lr) * 64 + kk + lg * 8);   \
      _Pragma("unroll")                                                           \
      for (int nf = 0; nf < 4; ++nf)                                              \
        bfr[nf] = *(const bf16x8*)(Bs + (wn + nf * 16 + lr) * 64 + kk + lg * 8);  \
      _Pragma("unroll")                                                           \
      for (int mf = 0; mf < 4; ++mf)                                              \
        _Pragma("unroll")                                                         \
        for (int nf = 0; nf < 4; ++nf)                                            \
          acc[mf][nf] = __builtin_amdgcn_mfma_f32_16x16x32_bf16(af[mf], bfr[nf],  \
                                                                acc[mf][nf], 0, 0, 0); \
    }                                                                             \
  }

// ---------------- bf16 GEMM: C[M,N] = A[M,K] * BT[N,K]^T + bias (+epilogue) ----
// EPI bits: 1 = exact GELU, 2 = add residual f32, 4 = write f32, 8 = write bf16
template <int EPI>
__global__ __launch_bounds__(256, 2)
void k_gemm(const bf16_t* __restrict__ A, const bf16_t* __restrict__ BT,
            const float* __restrict__ bias, const float* res,
            float* outF, bf16_t* outB, int M, int N, int K) {
  __shared__ __align__(16) bf16_t As[128 * 64];
  __shared__ __align__(16) bf16_t Bs[128 * 64];
  int nt = N >> 7;
  int bm = blockIdx.x / nt, bn = blockIdx.x % nt;
  int tid = threadIdx.x;
  int wave = tid >> 6, lane = tid & 63, lr = lane & 15, lg = lane >> 4;
  int wm = (wave >> 1) << 6, wn = (wave & 1) << 6;
  const bf16_t* Ab = A + (size_t)bm * 128 * K;
  const bf16_t* Bb = BT + (size_t)bn * 128 * K;
  GEMM_MAINLOOP(Ab, Bb, K)
  int row0 = bm * 128 + wm + lg * 4;
  int col0 = bn * 128 + wn + lr;
#pragma unroll
  for (int nf = 0; nf < 4; ++nf) {
    int c = col0 + nf * 16;
    float bi = bias[c];
#pragma unroll
    for (int mf = 0; mf < 4; ++mf) {
#pragma unroll
      for (int j = 0; j < 4; ++j) {
        int r = row0 + mf * 16 + j;
        size_t idx = (size_t)r * N + c;
        float v = acc[mf][nf][j] + bi;
        if (EPI & 1) v = gelu_f(v);
        if (EPI & 2) v += res[idx];
        if (EPI & 4) outF[idx] = v;
        if (EPI & 8) outB[idx] = (bf16_t)v;
      }
    }
  }
}

// ---------------- fused QKV GEMM: N = 2304 (2048 q | 128 k | 128 v) ----------
__global__ __launch_bounds__(256, 2)
void k_gemm_qkv(const bf16_t* __restrict__ A, const bf16_t* __restrict__ BT,
                const float* __restrict__ bq, const float* __restrict__ bk,
                const float* __restrict__ bv,
                bf16_t* __restrict__ qb, float* __restrict__ outk,
                float* __restrict__ outv, bf16_t* __restrict__ kbf,
                bf16_t* __restrict__ vbf, int K) {
  __shared__ __align__(16) bf16_t As[128 * 64];
  __shared__ __align__(16) bf16_t Bs[128 * 64];
  const int nt = NQKV >> 7;  // 18
  int bm = blockIdx.x / nt, bn = blockIdx.x % nt;
  int tid = threadIdx.x;
  int wave = tid >> 6, lane = tid & 63, lr = lane & 15, lg = lane >> 4;
  int wm = (wave >> 1) << 6, wn = (wave & 1) << 6;
  const bf16_t* Ab = A + (size_t)bm * 128 * K;
  const bf16_t* Bb = BT + (size_t)bn * 128 * K;
  GEMM_MAINLOOP(Ab, Bb, K)
  int row0 = bm * 128 + wm + lg * 4;
  int col0 = bn * 128 + wn + lr;
  if (bn < 16) {        // Q block -> qb bf16 [4096][2048]
#pragma unroll
    for (int nf = 0; nf < 4; ++nf) {
      int c = col0 + nf * 16;
      float bi = bq[c];
#pragma unroll
      for (int mf = 0; mf < 4; ++mf)
#pragma unroll
        for (int j = 0; j < 4; ++j) {
          int r = row0 + mf * 16 + j;
          qb[(size_t)r * DIMSZ + c] = (bf16_t)(acc[mf][nf][j] + bi);
        }
    }
  } else if (bn == 16) {  // K block -> outk f32 + kbf bf16, [4096][128]
#pragma unroll
    for (int nf = 0; nf < 4; ++nf) {
      int cc = col0 + nf * 16 - 2048;
      float bi = bk[cc];
#pragma unroll
      for (int mf = 0; mf < 4; ++mf)
#pragma unroll
        for (int j = 0; j < 4; ++j) {
          int r = row0 + mf * 16 + j;
          float v = acc[mf][nf][j] + bi;
          outk[(size_t)r * HD + cc] = v;
          kbf[(size_t)r * HD + cc] = (bf16_t)v;
        }
    }
  } else {               // V block -> outv f32 + vbf bf16
#pragma unroll
    for (int nf = 0; nf < 4; ++nf) {
      int cc = col0 + nf * 16 - 2176;
      float bi = bv[cc];
#pragma unroll
      for (int mf = 0; mf < 4; ++mf)
#pragma unroll
        for (int j = 0; j < 4; ++j) {
          int r = row0 + mf * 16 + j;
          float v = acc[mf][nf][j] + bi;
          outv[(size_t)r * HD + cc] = v;
          vbf[(size_t)r * HD + cc] = (bf16_t)v;
        }
    }
  }
}

// ---------------- causal flash attention (MQA) ----------------
// Block = 256 threads = 4 waves. Waves 0-1: 32-row q-tile p; waves 2-3: q-tile
// 63-p (causal work pairing -> every block does exactly 66 KV-tile-units).
// Each wave owns 16 q-rows. K and V^T MFMA B-fragments are read DIRECTLY from
// global (MQA: 16 heads share 1MB K/V per batch -> L2-resident). Only P takes
// an LDS round-trip (per-wave, row-padded 64->72 elems => conflict-free).
__global__ __launch_bounds__(256, 4)
void k_attn(const bf16_t* __restrict__ q, const bf16_t* __restrict__ k,
            const bf16_t* __restrict__ vt, bf16_t* __restrict__ ctx) {
  __shared__ bf16_t Pw[4][16][72];
  int p = blockIdx.x, h = blockIdx.y, b = blockIdx.z;
  int tid = threadIdx.x, wave = tid >> 6, lane = tid & 63, lr = lane & 15, lg = lane >> 4;
  int qt32 = (wave < 2) ? p : (63 - p);
  int qw = qt32 * 32 + (wave & 1) * 16;   // this wave's first q-row
  const bf16_t* qbase = q + ((size_t)(b * SEQ + qw + lr)) * DIMSZ + h * HD;
  bf16x8 qf[4];
#pragma unroll
  for (int kk = 0; kk < 4; ++kk) qf[kk] = *(const bf16x8*)(qbase + kk * 32 + lg * 8);
  f32x4 o[8] = {};
  float m_[4], l_[4];
#pragma unroll
  for (int j = 0; j < 4; ++j) { m_[j] = -3.0e38f; l_[j] = 0.f; }
  const bf16_t* kb = k + (size_t)b * SEQ * HD;
  const bf16_t* vb = vt + (size_t)b * HD * SEQ;
  int qglob0 = qw + lg * 4;
  int send = qw + 16;  // tiles with s0 <= last row of this wave
  for (int s0 = 0; s0 < send; s0 += 64) {
    // ---- QK^T: B-fragments straight from global K [s][128] ----
    f32x4 sf[4] = {};
#pragma unroll
    for (int nf = 0; nf < 4; ++nf) {
      const bf16_t* kr = kb + (size_t)(s0 + nf * 16 + lr) * HD + lg * 8;
#pragma unroll
      for (int kk = 0; kk < 4; ++kk)
        sf[nf] = __builtin_amdgcn_mfma_f32_16x16x32_bf16(
            qf[kk], *(const bf16x8*)(kr + kk * 32), sf[nf], 0, 0, 0);
    }
    // ---- scale + causal mask ----
#pragma unroll
    for (int nf = 0; nf < 4; ++nf) {
      int col = s0 + nf * 16 + lr;
#pragma unroll
      for (int j = 0; j < 4; ++j) {
        float v = sf[nf][j] * 0.088388347648318447f;
        sf[nf][j] = (col <= qglob0 + j) ? v : -3.0e38f;
      }
    }
    // ---- online softmax (rows live across lanes lr within each lg group) ----
    float mx[4];
#pragma unroll
    for (int j = 0; j < 4; ++j)
      mx[j] = fmaxf(fmaxf(sf[0][j], sf[1][j]), fmaxf(sf[2][j], sf[3][j]));
#pragma unroll
    for (int o_ = 1; o_ < 16; o_ <<= 1)
#pragma unroll
      for (int j = 0; j < 4; ++j) mx[j] = fmaxf(mx[j], __shfl_xor(mx[j], o_));
    float fsc[4], mn[4];
#pragma unroll
    for (int j = 0; j < 4; ++j) {
      mn[j] = fmaxf(m_[j], mx[j]);
      fsc[j] = __expf(m_[j] - mn[j]);
      m_[j] = mn[j];
    }
    float ps[4] = {0.f, 0.f, 0.f, 0.f};
#pragma unroll
    for (int nf = 0; nf < 4; ++nf)
#pragma unroll
      for (int j = 0; j < 4; ++j) {
        float pv = __expf(sf[nf][j] - mn[j]);
        ps[j] += pv;
        Pw[wave][lg * 4 + j][nf * 16 + lr] = (bf16_t)pv;
      }
#pragma unroll
    for (int o_ = 1; o_ < 16; o_ <<= 1)
#pragma unroll
      for (int j = 0; j < 4; ++j) ps[j] += __shfl_xor(ps[j], o_);
#pragma unroll
    for (int j = 0; j < 4; ++j) l_[j] = l_[j] * fsc[j] + ps[j];
#pragma unroll
    for (int df = 0; df < 8; ++df)
#pragma unroll
      for (int j = 0; j < 4; ++j) o[df][j] *= fsc[j];
    asm volatile("" ::: "memory");  // order Pw LDS write -> read
    bf16x8 pa[2];
#pragma unroll
    for (int kk = 0; kk < 2; ++kk)
      pa[kk] = *(const bf16x8*)(&Pw[wave][lr][kk * 32 + lg * 8]);
    // ---- PV: B-fragments straight from global V^T [d][T] ----
#pragma unroll
    for (int df = 0; df < 8; ++df) {
      const bf16_t* vr = vb + (size_t)(df * 16 + lr) * SEQ + s0 + lg * 8;
#pragma unroll
      for (int kk = 0; kk < 2; ++kk)
        o[df] = __builtin_amdgcn_mfma_f32_16x16x32_bf16(
            pa[kk], *(const bf16x8*)(vr + kk * 32), o[df], 0, 0, 0);
    }
  }
  bf16_t* cb = ctx + ((size_t)(b * SEQ + qw)) * DIMSZ + h * HD;
#pragma unroll
  for (int df = 0; df < 8; ++df)
#pragma unroll
    for (int j = 0; j < 4; ++j)
      cb[(size_t)(lg * 4 + j) * DIMSZ + df * 16 + lr] = (bf16_t)(o[df][j] / l_[j]);
}

extern "C" void kernel_launch(void* const* d_in, const int* in_sizes, int n_in,
                              void* d_out, int out_size, void* d_ws, size_t ws_size,
                              hipStream_t stream) {
  const float* x   = (const float*)d_in[0];
  const float* wq  = (const float*)d_in[2];
  const float* bq  = (const float*)d_in[3];
  const float* wk  = (const float*)d_in[4];
  const float* bk  = (const float*)d_in[5];
  const float* wv  = (const float*)d_in[6];
  const float* bv  = (const float*)d_in[7];
  const float* wo  = (const float*)d_in[8];
  const float* bo  = (const float*)d_in[9];
  const float* g1  = (const float*)d_in[10];
  const float* be1 = (const float*)d_in[11];
  const float* g2  = (const float*)d_in[12];
  const float* be2 = (const float*)d_in[13];
  const float* w1  = (const float*)d_in[14];
  const float* bb1 = (const float*)d_in[15];
  const float* w2  = (const float*)d_in[16];
  const float* bb2 = (const float*)d_in[17];

  float* outx = (float*)d_out;                       // [4096][2048] (also x1 scratch)
  float* outk = outx + (size_t)MROWS * DIMSZ;        // [4096][128]
  float* outv = outk + (size_t)MROWS * HD;           // [4096][128]

  char* p = (char*)d_ws;
  auto alloc = [&](size_t bytes) -> char* {
    char* r = p;
    p += (bytes + 255) & ~(size_t)255;
    return r;
  };
  bf16_t* wqkvT = (bf16_t*)alloc((size_t)NQKV * DIMSZ * 2);   // [2304][2048]
  bf16_t* woT = (bf16_t*)alloc((size_t)DIMSZ * DIMSZ * 2);
  bf16_t* w1T = (bf16_t*)alloc((size_t)FFDIM * DIMSZ * 2);
  bf16_t* w2T = (bf16_t*)alloc((size_t)DIMSZ * FFDIM * 2);
  bf16_t* hb  = (bf16_t*)alloc((size_t)MROWS * DIMSZ * 2);  // h, later ctx
  bf16_t* qb  = (bf16_t*)alloc((size_t)MROWS * DIMSZ * 2);  // q, later h2
  bf16_t* kbf = (bf16_t*)alloc((size_t)MROWS * HD * 2);
  bf16_t* vbf = (bf16_t*)alloc((size_t)MROWS * HD * 2);
  bf16_t* vtb = (bf16_t*)alloc((size_t)BATCH * HD * SEQ * 2);
  bf16_t* f1b = (bf16_t*)alloc((size_t)MROWS * FFDIM * 2);
  (void)ws_size; (void)in_sizes; (void)n_in; (void)out_size;

  dim3 blk(256);
  // weight transposes / bf16 conversion; wq/wk/wv land in one [2304][2048]
  k_transpose_f32_bf16<<<dim3(DIMSZ / 32, DIMSZ / 32), blk, 0, stream>>>(wq, wqkvT, DIMSZ, DIMSZ);
  k_transpose_f32_bf16<<<dim3(HD / 32, DIMSZ / 32), blk, 0, stream>>>(wk, wqkvT + (size_t)2048 * DIMSZ, DIMSZ, HD);
  k_transpose_f32_bf16<<<dim3(HD / 32, DIMSZ / 32), blk, 0, stream>>>(wv, wqkvT + (size_t)2176 * DIMSZ, DIMSZ, HD);
  k_transpose_f32_bf16<<<dim3(DIMSZ / 32, DIMSZ / 32), blk, 0, stream>>>(wo, woT, DIMSZ, DIMSZ);
  k_transpose_f32_bf16<<<dim3(FFDIM / 32, DIMSZ / 32), blk, 0, stream>>>(w1, w1T, DIMSZ, FFDIM);
  k_transpose_f32_bf16<<<dim3(DIMSZ / 32, FFDIM / 32), blk, 0, stream>>>(w2, w2T, FFDIM, DIMSZ);
  // ln1: x -> h(bf16)
  k_layernorm<<<MROWS, blk, 0, stream>>>(x, g1, be1, hb);
  // fused q,k,v projection (N=2304)
  k_gemm_qkv<<<(MROWS / 128) * (NQKV / 128), blk, 0, stream>>>(
      hb, wqkvT, bq, bk, bv, qb, outk, outv, kbf, vbf, DIMSZ);
  k_transpose_v<<<dim3(SEQ / 32, HD / 32, BATCH), blk, 0, stream>>>(vbf, vtb);
  // attention -> ctx (reuse hb)
  k_attn<<<dim3(SEQ / 32 / 2, NH, BATCH), blk, 0, stream>>>(qb, kbf, vtb, hb);
  // o-proj + residual -> outx (x1)
  k_gemm<6><<<(MROWS / 128) * (DIMSZ / 128), blk, 0, stream>>>(hb, woT, bo, x, outx, nullptr, MROWS, DIMSZ, DIMSZ);
  // ln2: x1 -> h2 (reuse qb)
  k_layernorm<<<MROWS, blk, 0, stream>>>(outx, g2, be2, qb);
  // ffn1 + exact gelu -> f1b (bf16)
  k_gemm<9><<<(MROWS / 128) * (FFDIM / 128), blk, 0, stream>>>(qb, w1T, bb1, nullptr, nullptr, f1b, MROWS, FFDIM, DIMSZ);
  // ffn2 + residual -> outx (final x)
  k_gemm<6><<<(MROWS / 128) * (DIMSZ / 128), blk, 0, stream>>>(f1b, w2T, bb2, outx, outx, nullptr, MROWS, DIMSZ, FFDIM);
}

// Round 3
// 711.734 us; speedup vs baseline: 1.3373x; 1.2645x over previous
//
#include <hip/hip_runtime.h>
#include <stdint.h>

#define DIMSZ 2048
#define HD 128
#define NH 16
#define BATCH 2
#define SEQ 2048
#define MROWS (BATCH*SEQ)   // 4096
#define FFDIM (4*DIMSZ)     // 8192
#define NQKV (DIMSZ + 2*HD) // 2304

typedef float f32x4 __attribute__((ext_vector_type(4)));
typedef __bf16 bf16x8 __attribute__((ext_vector_type(8)));
typedef __bf16 bf16_t;

__device__ __forceinline__ void async16(const void* g, void* l) {
  __builtin_amdgcn_global_load_lds(
      (const __attribute__((address_space(1))) void*)(uintptr_t)g,
      (__attribute__((address_space(3))) void*)(uint32_t)(uintptr_t)l,
      16, 0, 0);
}

__device__ __forceinline__ float gelu_f(float x) {
  return 0.5f * x * (1.0f + erff(x * 0.70710678118654752f));
}

// ---------------- transpose f32 (R x C) -> bf16 (C x R) ----------------
__global__ __launch_bounds__(256)
void k_transpose_f32_bf16(const float* __restrict__ src, bf16_t* __restrict__ dst,
                          int R, int C) {
  __shared__ float tile[32][33];
  int c0 = blockIdx.x * 32, r0 = blockIdx.y * 32;
  int tx = threadIdx.x & 31, ty = threadIdx.x >> 5;
#pragma unroll
  for (int i = 0; i < 32; i += 8)
    tile[ty + i][tx] = src[(size_t)(r0 + ty + i) * C + (c0 + tx)];
  __syncthreads();
#pragma unroll
  for (int i = 0; i < 32; i += 8)
    dst[(size_t)(c0 + ty + i) * R + (r0 + tx)] = (bf16_t)tile[tx][ty + i];
}

// ---------------- transpose v bf16 [B*T][128] -> vt [B][128][T] ----------------
__global__ __launch_bounds__(256)
void k_transpose_v(const bf16_t* __restrict__ v, bf16_t* __restrict__ vt) {
  __shared__ bf16_t tile[32][33];
  int b = blockIdx.z;
  int t0 = blockIdx.x * 32, d0 = blockIdx.y * 32;
  int tx = threadIdx.x & 31, ty = threadIdx.x >> 5;
#pragma unroll
  for (int i = 0; i < 32; i += 8)
    tile[ty + i][tx] = v[((size_t)(b * SEQ + t0 + ty + i)) * HD + d0 + tx];
  __syncthreads();
#pragma unroll
  for (int i = 0; i < 32; i += 8)
    vt[((size_t)(b * HD + d0 + ty + i)) * SEQ + t0 + tx] = tile[tx][ty + i];
}

// ---------------- layernorm f32 -> bf16 ----------------
__global__ __launch_bounds__(256)
void k_layernorm(const float* __restrict__ x, const float* __restrict__ g,
                 const float* __restrict__ bb, bf16_t* __restrict__ out) {
  int row = blockIdx.x;
  const float* xr = x + (size_t)row * DIMSZ;
  int t = threadIdx.x;
  float vals[8];
  float s = 0.f, s2 = 0.f;
#pragma unroll
  for (int i = 0; i < 8; ++i) {
    float v = xr[t + i * 256];
    vals[i] = v; s += v; s2 += v * v;
  }
#pragma unroll
  for (int o = 1; o < 64; o <<= 1) { s += __shfl_xor(s, o); s2 += __shfl_xor(s2, o); }
  __shared__ float red[8];
  if ((t & 63) == 0) { red[t >> 6] = s; red[4 + (t >> 6)] = s2; }
  __syncthreads();
  s = red[0] + red[1] + red[2] + red[3];
  s2 = red[4] + red[5] + red[6] + red[7];
  float mu = s * (1.0f / DIMSZ);
  float rstd = rsqrtf(s2 * (1.0f / DIMSZ) - mu * mu + 1e-5f);
  bf16_t* orow = out + (size_t)row * DIMSZ;
#pragma unroll
  for (int i = 0; i < 8; ++i) {
    int c = t + i * 256;
    orow[c] = (bf16_t)((vals[i] - mu) * rstd * g[c] + bb[c]);
  }
}

// ---------------- GEMM main loop (shared by both GEMM kernels) ----------------
#define GEMM_MAINLOOP(Ab, Bb, K)                                                  \
  f32x4 acc[4][4] = {};                                                           \
  for (int k0 = 0; k0 < (K); k0 += 64) {                                          \
    __syncthreads();                                                              \
    _Pragma("unroll")                                                             \
    for (int i = 0; i < 4; ++i) {                                                 \
      int flat = (i * 256 + tid) * 8;                                             \
      int r = flat >> 6, c = flat & 63;                                           \
      async16((Ab) + (size_t)r * (K) + k0 + c, (void*)(As + flat));               \
      async16((Bb) + (size_t)r * (K) + k0 + c, (void*)(Bs + flat));               \
    }                                                                             \
    __syncthreads();                                                              \
    _Pragma("unroll")                                                             \
    for (int kk = 0; kk < 64; kk += 32) {                                         \
      bf16x8 af[4], bfr[4];                                                       \
      _Pragma("unroll")                                                           \
      for (int mf = 0; mf < 4; ++mf)                                              \
        af[mf] = *(const bf16x8*)(As + (wm + mf * 16 + lr) * 64 + kk + lg * 8);   \
      _Pragma("unroll")                                                           \
      for (int nf = 0; nf < 4; ++nf)                                              \
        bfr[nf] = *(const bf16x8*)(Bs + (wn + nf * 16 + lr) * 64 + kk + lg * 8);  \
      _Pragma("unroll")                                                           \
      for (int mf = 0; mf < 4; ++mf)                                              \
        _Pragma("unroll")                                                         \
        for (int nf = 0; nf < 4; ++nf)                                            \
          acc[mf][nf] = __builtin_amdgcn_mfma_f32_16x16x32_bf16(af[mf], bfr[nf],  \
                                                                acc[mf][nf], 0, 0, 0); \
    }                                                                             \
  }

// ---------------- bf16 GEMM: C[M,N] = A[M,K] * BT[N,K]^T + bias (+epilogue) ----
// EPI bits: 1 = exact GELU, 2 = add residual f32, 4 = write f32, 8 = write bf16
template <int EPI>
__global__ __launch_bounds__(256, 2)
void k_gemm(const bf16_t* __restrict__ A, const bf16_t* __restrict__ BT,
            const float* __restrict__ bias, const float* res,
            float* outF, bf16_t* outB, int M, int N, int K) {
  __shared__ __align__(16) bf16_t As[128 * 64];
  __shared__ __align__(16) bf16_t Bs[128 * 64];
  int nt = N >> 7;
  int bm = blockIdx.x / nt, bn = blockIdx.x % nt;
  int tid = threadIdx.x;
  int wave = tid >> 6, lane = tid & 63, lr = lane & 15, lg = lane >> 4;
  int wm = (wave >> 1) << 6, wn = (wave & 1) << 6;
  const bf16_t* Ab = A + (size_t)bm * 128 * K;
  const bf16_t* Bb = BT + (size_t)bn * 128 * K;
  GEMM_MAINLOOP(Ab, Bb, K)
  int row0 = bm * 128 + wm + lg * 4;
  int col0 = bn * 128 + wn + lr;
#pragma unroll
  for (int nf = 0; nf < 4; ++nf) {
    int c = col0 + nf * 16;
    float bi = bias[c];
#pragma unroll
    for (int mf = 0; mf < 4; ++mf) {
#pragma unroll
      for (int j = 0; j < 4; ++j) {
        int r = row0 + mf * 16 + j;
        size_t idx = (size_t)r * N + c;
        float v = acc[mf][nf][j] + bi;
        if (EPI & 1) v = gelu_f(v);
        if (EPI & 2) v += res[idx];
        if (EPI & 4) outF[idx] = v;
        if (EPI & 8) outB[idx] = (bf16_t)v;
      }
    }
  }
}

// ---------------- fused QKV GEMM: N = 2304 (2048 q | 128 k | 128 v) ----------
__global__ __launch_bounds__(256, 2)
void k_gemm_qkv(const bf16_t* __restrict__ A, const bf16_t* __restrict__ BT,
                const float* __restrict__ bq, const float* __restrict__ bk,
                const float* __restrict__ bv,
                bf16_t* __restrict__ qb, float* __restrict__ outk,
                float* __restrict__ outv, bf16_t* __restrict__ kbf,
                bf16_t* __restrict__ vbf, int K) {
  __shared__ __align__(16) bf16_t As[128 * 64];
  __shared__ __align__(16) bf16_t Bs[128 * 64];
  const int nt = NQKV >> 7;  // 18
  int bm = blockIdx.x / nt, bn = blockIdx.x % nt;
  int tid = threadIdx.x;
  int wave = tid >> 6, lane = tid & 63, lr = lane & 15, lg = lane >> 4;
  int wm = (wave >> 1) << 6, wn = (wave & 1) << 6;
  const bf16_t* Ab = A + (size_t)bm * 128 * K;
  const bf16_t* Bb = BT + (size_t)bn * 128 * K;
  GEMM_MAINLOOP(Ab, Bb, K)
  int row0 = bm * 128 + wm + lg * 4;
  int col0 = bn * 128 + wn + lr;
  if (bn < 16) {        // Q block -> qb bf16 [4096][2048]
#pragma unroll
    for (int nf = 0; nf < 4; ++nf) {
      int c = col0 + nf * 16;
      float bi = bq[c];
#pragma unroll
      for (int mf = 0; mf < 4; ++mf)
#pragma unroll
        for (int j = 0; j < 4; ++j) {
          int r = row0 + mf * 16 + j;
          qb[(size_t)r * DIMSZ + c] = (bf16_t)(acc[mf][nf][j] + bi);
        }
    }
  } else if (bn == 16) {  // K block -> outk f32 + kbf bf16, [4096][128]
#pragma unroll
    for (int nf = 0; nf < 4; ++nf) {
      int cc = col0 + nf * 16 - 2048;
      float bi = bk[cc];
#pragma unroll
      for (int mf = 0; mf < 4; ++mf)
#pragma unroll
        for (int j = 0; j < 4; ++j) {
          int r = row0 + mf * 16 + j;
          float v = acc[mf][nf][j] + bi;
          outk[(size_t)r * HD + cc] = v;
          kbf[(size_t)r * HD + cc] = (bf16_t)v;
        }
    }
  } else {               // V block -> outv f32 + vbf bf16
#pragma unroll
    for (int nf = 0; nf < 4; ++nf) {
      int cc = col0 + nf * 16 - 2176;
      float bi = bv[cc];
#pragma unroll
      for (int mf = 0; mf < 4; ++mf)
#pragma unroll
        for (int j = 0; j < 4; ++j) {
          int r = row0 + mf * 16 + j;
          float v = acc[mf][nf][j] + bi;
          outv[(size_t)r * HD + cc] = v;
          vbf[(size_t)r * HD + cc] = (bf16_t)v;
        }
    }
  }
}

// ---------------- causal flash attention (MQA) ----------------
// Block = 4 waves sharing one 64-row q-tile (16 rows/wave). Block p handles
// q-tiles {p, 31-p} sequentially -> uniform 33 KV-tiles/block. K [64][128] and
// V^T [128][64] staged in LDS (double-buffered) via global_load_lds with
// chunk-XOR swizzle (pre-swizzled global source + XOR on ds_read). 2-phase
// pipeline: STAGE(t+1) issued before compute(t), one barrier per tile.
__global__ __launch_bounds__(256, 2)
void k_attn(const bf16_t* __restrict__ q, const bf16_t* __restrict__ k,
            const bf16_t* __restrict__ vt, bf16_t* __restrict__ ctx) {
  __shared__ __align__(16) bf16_t Ks[2][64 * 128];
  __shared__ __align__(16) bf16_t Vs[2][128 * 64];
  __shared__ bf16_t Pw[4][16][72];
  int pp = blockIdx.x, h = blockIdx.y, b = blockIdx.z;
  int tid = threadIdx.x, wave = tid >> 6, lane = tid & 63, lr = lane & 15, lg = lane >> 4;
  const bf16_t* kb = k + (size_t)b * SEQ * HD;
  const bf16_t* vb = vt + (size_t)b * HD * SEQ;

  // per-thread staging coordinates (4 x async16 each for K and V)
  //  K tile: flat elem = (i*256+tid)*8 ; r=flat>>7, c=flat&127
  //  V tile: flat elem = (i*256+tid)*8 ; r=flat>>6, c=flat&63
#define STAGE_TILE(buf, s0_)                                                      \
  {                                                                               \
    _Pragma("unroll")                                                             \
    for (int i = 0; i < 4; ++i) {                                                 \
      int flat = (i * 256 + tid) * 8;                                             \
      int kr = flat >> 7, kc = flat & 127;                                        \
      int ksrc = (((kc >> 3) ^ (kr & 7)) << 3) | (kc & 7);                        \
      async16(kb + (size_t)((s0_) + kr) * HD + ksrc, (void*)(Ks[buf] + flat));    \
      int vr = flat >> 6, vc = flat & 63;                                         \
      int vsrc = (((vc >> 3) ^ (vr & 7)) << 3) | (vc & 7);                        \
      async16(vb + (size_t)vr * SEQ + (s0_) + vsrc, (void*)(Vs[buf] + flat));     \
    }                                                                             \
  }

  for (int half = 0; half < 2; ++half) {
    int qt = half ? (31 - pp) : pp;
    int q0 = qt * 64;
    int qw = q0 + wave * 16;
    const bf16_t* qbase = q + ((size_t)(b * SEQ + qw + lr)) * DIMSZ + h * HD;
    bf16x8 qf[4];
#pragma unroll
    for (int kk = 0; kk < 4; ++kk) qf[kk] = *(const bf16x8*)(qbase + kk * 32 + lg * 8);
    f32x4 o[8] = {};
    float m_[4], l_[4];
#pragma unroll
    for (int j = 0; j < 4; ++j) { m_[j] = -3.0e38f; l_[j] = 0.f; }
    int qglob0 = qw + lg * 4;
    int ntiles = qt + 1;  // 64-wide KV tiles

    STAGE_TILE(0, 0)
    __syncthreads();
    for (int t = 0; t < ntiles; ++t) {
      int cur = t & 1;
      if (t + 1 < ntiles) STAGE_TILE(cur ^ 1, (t + 1) * 64)
      int s0 = t * 64;
      const bf16_t* Kc = Ks[cur];
      const bf16_t* Vc = Vs[cur];
      // ---- QK^T from swizzled LDS ----
      f32x4 sf[4] = {};
#pragma unroll
      for (int nf = 0; nf < 4; ++nf) {
        int R = nf * 16 + lr;
#pragma unroll
        for (int kk = 0; kk < 4; ++kk)
          sf[nf] = __builtin_amdgcn_mfma_f32_16x16x32_bf16(
              qf[kk],
              *(const bf16x8*)(Kc + R * 128 + (((kk * 4 + lg) ^ (R & 7)) << 3)),
              sf[nf], 0, 0, 0);
      }
      // ---- scale + causal mask ----
#pragma unroll
      for (int nf = 0; nf < 4; ++nf) {
        int col = s0 + nf * 16 + lr;
#pragma unroll
        for (int j = 0; j < 4; ++j) {
          float v = sf[nf][j] * 0.088388347648318447f;
          sf[nf][j] = (col <= qglob0 + j) ? v : -3.0e38f;
        }
      }
      // ---- online softmax ----
      float mx[4];
#pragma unroll
      for (int j = 0; j < 4; ++j)
        mx[j] = fmaxf(fmaxf(sf[0][j], sf[1][j]), fmaxf(sf[2][j], sf[3][j]));
#pragma unroll
      for (int o_ = 1; o_ < 16; o_ <<= 1)
#pragma unroll
        for (int j = 0; j < 4; ++j) mx[j] = fmaxf(mx[j], __shfl_xor(mx[j], o_));
      float fsc[4], mn[4];
#pragma unroll
      for (int j = 0; j < 4; ++j) {
        mn[j] = fmaxf(m_[j], mx[j]);
        fsc[j] = __expf(m_[j] - mn[j]);
        m_[j] = mn[j];
      }
      float ps[4] = {0.f, 0.f, 0.f, 0.f};
#pragma unroll
      for (int nf = 0; nf < 4; ++nf)
#pragma unroll
        for (int j = 0; j < 4; ++j) {
          float pv = __expf(sf[nf][j] - mn[j]);
          ps[j] += pv;
          Pw[wave][lg * 4 + j][nf * 16 + lr] = (bf16_t)pv;
        }
#pragma unroll
      for (int o_ = 1; o_ < 16; o_ <<= 1)
#pragma unroll
        for (int j = 0; j < 4; ++j) ps[j] += __shfl_xor(ps[j], o_);
#pragma unroll
      for (int j = 0; j < 4; ++j) l_[j] = l_[j] * fsc[j] + ps[j];
#pragma unroll
      for (int df = 0; df < 8; ++df)
#pragma unroll
        for (int j = 0; j < 4; ++j) o[df][j] *= fsc[j];
      asm volatile("" ::: "memory");  // order Pw LDS write -> read
      bf16x8 pa[2];
#pragma unroll
      for (int kk = 0; kk < 2; ++kk)
        pa[kk] = *(const bf16x8*)(&Pw[wave][lr][kk * 32 + lg * 8]);
      // ---- PV from swizzled LDS V^T ----
#pragma unroll
      for (int df = 0; df < 8; ++df) {
        int R = df * 16 + lr;
#pragma unroll
        for (int kk = 0; kk < 2; ++kk)
          o[df] = __builtin_amdgcn_mfma_f32_16x16x32_bf16(
              pa[kk],
              *(const bf16x8*)(Vc + R * 64 + (((kk * 4 + lg) ^ (R & 7)) << 3)),
              o[df], 0, 0, 0);
      }
      __syncthreads();  // staged t+1 complete + all waves done with buf[cur]
    }
    bf16_t* cb = ctx + ((size_t)(b * SEQ + qw)) * DIMSZ + h * HD;
#pragma unroll
    for (int df = 0; df < 8; ++df)
#pragma unroll
      for (int j = 0; j < 4; ++j)
        cb[(size_t)(lg * 4 + j) * DIMSZ + df * 16 + lr] = (bf16_t)(o[df][j] / l_[j]);
  }
#undef STAGE_TILE
}

extern "C" void kernel_launch(void* const* d_in, const int* in_sizes, int n_in,
                              void* d_out, int out_size, void* d_ws, size_t ws_size,
                              hipStream_t stream) {
  const float* x   = (const float*)d_in[0];
  const float* wq  = (const float*)d_in[2];
  const float* bq  = (const float*)d_in[3];
  const float* wk  = (const float*)d_in[4];
  const float* bk  = (const float*)d_in[5];
  const float* wv  = (const float*)d_in[6];
  const float* bv  = (const float*)d_in[7];
  const float* wo  = (const float*)d_in[8];
  const float* bo  = (const float*)d_in[9];
  const float* g1  = (const float*)d_in[10];
  const float* be1 = (const float*)d_in[11];
  const float* g2  = (const float*)d_in[12];
  const float* be2 = (const float*)d_in[13];
  const float* w1  = (const float*)d_in[14];
  const float* bb1 = (const float*)d_in[15];
  const float* w2  = (const float*)d_in[16];
  const float* bb2 = (const float*)d_in[17];

  float* outx = (float*)d_out;                       // [4096][2048] (also x1 scratch)
  float* outk = outx + (size_t)MROWS * DIMSZ;        // [4096][128]
  float* outv = outk + (size_t)MROWS * HD;           // [4096][128]

  char* p = (char*)d_ws;
  auto alloc = [&](size_t bytes) -> char* {
    char* r = p;
    p += (bytes + 255) & ~(size_t)255;
    return r;
  };
  bf16_t* wqkvT = (bf16_t*)alloc((size_t)NQKV * DIMSZ * 2);   // [2304][2048]
  bf16_t* woT = (bf16_t*)alloc((size_t)DIMSZ * DIMSZ * 2);
  bf16_t* w1T = (bf16_t*)alloc((size_t)FFDIM * DIMSZ * 2);
  bf16_t* w2T = (bf16_t*)alloc((size_t)DIMSZ * FFDIM * 2);
  bf16_t* hb  = (bf16_t*)alloc((size_t)MROWS * DIMSZ * 2);  // h, later ctx
  bf16_t* qb  = (bf16_t*)alloc((size_t)MROWS * DIMSZ * 2);  // q, later h2
  bf16_t* kbf = (bf16_t*)alloc((size_t)MROWS * HD * 2);
  bf16_t* vbf = (bf16_t*)alloc((size_t)MROWS * HD * 2);
  bf16_t* vtb = (bf16_t*)alloc((size_t)BATCH * HD * SEQ * 2);
  bf16_t* f1b = (bf16_t*)alloc((size_t)MROWS * FFDIM * 2);
  (void)ws_size; (void)in_sizes; (void)n_in; (void)out_size;

  dim3 blk(256);
  // weight transposes / bf16 conversion; wq/wk/wv land in one [2304][2048]
  k_transpose_f32_bf16<<<dim3(DIMSZ / 32, DIMSZ / 32), blk, 0, stream>>>(wq, wqkvT, DIMSZ, DIMSZ);
  k_transpose_f32_bf16<<<dim3(HD / 32, DIMSZ / 32), blk, 0, stream>>>(wk, wqkvT + (size_t)2048 * DIMSZ, DIMSZ, HD);
  k_transpose_f32_bf16<<<dim3(HD / 32, DIMSZ / 32), blk, 0, stream>>>(wv, wqkvT + (size_t)2176 * DIMSZ, DIMSZ, HD);
  k_transpose_f32_bf16<<<dim3(DIMSZ / 32, DIMSZ / 32), blk, 0, stream>>>(wo, woT, DIMSZ, DIMSZ);
  k_transpose_f32_bf16<<<dim3(FFDIM / 32, DIMSZ / 32), blk, 0, stream>>>(w1, w1T, DIMSZ, FFDIM);
  k_transpose_f32_bf16<<<dim3(DIMSZ / 32, FFDIM / 32), blk, 0, stream>>>(w2, w2T, FFDIM, DIMSZ);
  // ln1: x -> h(bf16)
  k_layernorm<<<MROWS, blk, 0, stream>>>(x, g1, be1, hb);
  // fused q,k,v projection (N=2304)
  k_gemm_qkv<<<(MROWS / 128) * (NQKV / 128), blk, 0, stream>>>(
      hb, wqkvT, bq, bk, bv, qb, outk, outv, kbf, vbf, DIMSZ);
  k_transpose_v<<<dim3(SEQ / 32, HD / 32, BATCH), blk, 0, stream>>>(vbf, vtb);
  // attention -> ctx (reuse hb)
  k_attn<<<dim3(SEQ / 64 / 2, NH, BATCH), blk, 0, stream>>>(qb, kbf, vtb, hb);
  // o-proj + residual -> outx (x1)
  k_gemm<6><<<(MROWS / 128) * (DIMSZ / 128), blk, 0, stream>>>(hb, woT, bo, x, outx, nullptr, MROWS, DIMSZ, DIMSZ);
  // ln2: x1 -> h2 (reuse qb)
  k_layernorm<<<MROWS, blk, 0, stream>>>(outx, g2, be2, qb);
  // ffn1 + exact gelu -> f1b (bf16)
  k_gemm<9><<<(MROWS / 128) * (FFDIM / 128), blk, 0, stream>>>(qb, w1T, bb1, nullptr, nullptr, f1b, MROWS, FFDIM, DIMSZ);
  // ffn2 + residual -> outx (final x)
  k_gemm<6><<<(MROWS / 128) * (DIMSZ / 128), blk, 0, stream>>>(f1b, w2T, bb2, outx, outx, nullptr, MROWS, DIMSZ, FFDIM);
}

// Round 4
// 591.290 us; speedup vs baseline: 1.6097x; 1.2037x over previous
//
#include <hip/hip_runtime.h>
#include <stdint.h>

#define DIMSZ 2048
#define HD 128
#define NH 16
#define BATCH 2
#define SEQ 2048
#define MROWS (BATCH*SEQ)   // 4096
#define FFDIM (4*DIMSZ)     // 8192
#define NQKV (DIMSZ + 2*HD) // 2304

typedef float f32x4 __attribute__((ext_vector_type(4)));
typedef __bf16 bf16x8 __attribute__((ext_vector_type(8)));
typedef __bf16 bf16_t;

__device__ __forceinline__ void async16(const void* g, void* l) {
  __builtin_amdgcn_global_load_lds(
      (const __attribute__((address_space(1))) void*)(uintptr_t)g,
      (__attribute__((address_space(3))) void*)(uint32_t)(uintptr_t)l,
      16, 0, 0);
}

__device__ __forceinline__ float gelu_f(float x) {
  return 0.5f * x * (1.0f + erff(x * 0.70710678118654752f));
}

__device__ __forceinline__ void hard_barrier() {
  asm volatile("" ::: "memory");
  __builtin_amdgcn_s_barrier();
  asm volatile("" ::: "memory");
}

// ---------------- transpose f32 (R x C) -> bf16 (C x R) ----------------
__global__ __launch_bounds__(256)
void k_transpose_f32_bf16(const float* __restrict__ src, bf16_t* __restrict__ dst,
                          int R, int C) {
  __shared__ float tile[32][33];
  int c0 = blockIdx.x * 32, r0 = blockIdx.y * 32;
  int tx = threadIdx.x & 31, ty = threadIdx.x >> 5;
#pragma unroll
  for (int i = 0; i < 32; i += 8)
    tile[ty + i][tx] = src[(size_t)(r0 + ty + i) * C + (c0 + tx)];
  __syncthreads();
#pragma unroll
  for (int i = 0; i < 32; i += 8)
    dst[(size_t)(c0 + ty + i) * R + (r0 + tx)] = (bf16_t)tile[tx][ty + i];
}

// ---------------- transpose v bf16 [B*T][128] -> vt [B][128][T] ----------------
__global__ __launch_bounds__(256)
void k_transpose_v(const bf16_t* __restrict__ v, bf16_t* __restrict__ vt) {
  __shared__ bf16_t tile[32][33];
  int b = blockIdx.z;
  int t0 = blockIdx.x * 32, d0 = blockIdx.y * 32;
  int tx = threadIdx.x & 31, ty = threadIdx.x >> 5;
#pragma unroll
  for (int i = 0; i < 32; i += 8)
    tile[ty + i][tx] = v[((size_t)(b * SEQ + t0 + ty + i)) * HD + d0 + tx];
  __syncthreads();
#pragma unroll
  for (int i = 0; i < 32; i += 8)
    vt[((size_t)(b * HD + d0 + ty + i)) * SEQ + t0 + tx] = tile[tx][ty + i];
}

// ---------------- layernorm f32 -> bf16 ----------------
__global__ __launch_bounds__(256)
void k_layernorm(const float* __restrict__ x, const float* __restrict__ g,
                 const float* __restrict__ bb, bf16_t* __restrict__ out) {
  int row = blockIdx.x;
  const float* xr = x + (size_t)row * DIMSZ;
  int t = threadIdx.x;
  float vals[8];
  float s = 0.f, s2 = 0.f;
#pragma unroll
  for (int i = 0; i < 8; ++i) {
    float v = xr[t + i * 256];
    vals[i] = v; s += v; s2 += v * v;
  }
#pragma unroll
  for (int o = 1; o < 64; o <<= 1) { s += __shfl_xor(s, o); s2 += __shfl_xor(s2, o); }
  __shared__ float red[8];
  if ((t & 63) == 0) { red[t >> 6] = s; red[4 + (t >> 6)] = s2; }
  __syncthreads();
  s = red[0] + red[1] + red[2] + red[3];
  s2 = red[4] + red[5] + red[6] + red[7];
  float mu = s * (1.0f / DIMSZ);
  float rstd = rsqrtf(s2 * (1.0f / DIMSZ) - mu * mu + 1e-5f);
  bf16_t* orow = out + (size_t)row * DIMSZ;
#pragma unroll
  for (int i = 0; i < 8; ++i) {
    int c = t + i * 256;
    orow[c] = (bf16_t)((vals[i] - mu) * rstd * g[c] + bb[c]);
  }
}

// =====================================================================
// 8-phase 256xBN GEMM main loop (T2+T3+T4+T5 stack, plain HIP).
// FN = n-frags per wave (4 -> BN=256, 2 -> BN=128). BK=64, 512 threads,
// 8 waves (2M x 4N), per-wave output 128 x FN*16.
// LDS: A [2buf][2half][128][64], B [2buf][BH half][128][64], BH=FN/2.
// XOR swizzle: phys col = logical col ^ ((row&7)<<3); applied on the
// global SOURCE address of global_load_lds (dest linear) and on ds_read.
// Schedule per iteration (2 K-tiles: T0->buf0, T1->buf1), phases P1..P8:
//   reads: P1: a[0-7]kk0 + b[*][kk0,kk1] (tile0); P3: a[0-7]kk1;
//          P5/P7 same for tile1.
//   stages: P1:T(2i+1).A1  P2:T(2i+2).B0  P3:T(2i+2).B1  P4:T(2i+2).A0
//           P5:T(2i+2).A1  P6:T(2i+3).B0  P7:T(2i+3).B1  P8:T(2i+3).A0
//   vmcnt(6) [BH=2] / vmcnt(4) [BH=1] at P4 and P8 only; vmcnt(0) at P4
//   of the last iteration. Raw s_barrier x2 per phase; setprio around MFMA.
// =====================================================================
template <int FN>
__device__ __forceinline__ void gemm8_loop(
    const bf16_t* __restrict__ A, const bf16_t* __restrict__ BT, int K,
    int bm, int bn, f32x4 (&acc)[8][FN], bf16_t* sh) {
  constexpr int BH = FN >> 1;
  constexpr int BN = FN * 64;
  const int tid = threadIdx.x;
  const int lane = tid & 63, lr = lane & 15, lg = lane >> 4;
  const int wave = tid >> 6, wm = wave >> 2, wn = wave & 3;
  bf16_t* const Ab0 = sh;            // [(c*2+h)*8192]
  bf16_t* const Bb0 = sh + 32768;    // [(c*BH+h)*8192]
  const bf16_t* const Ag = A + (size_t)bm * 256 * K;
  const bf16_t* const Bg = BT + (size_t)bn * BN * K;

  auto stage = [&](const bf16_t* gbase, bf16_t* lbase, int h, int t) {
#pragma unroll
    for (int j = 0; j < 2; ++j) {
      int flat = (tid + j * 512) * 8;
      int r = flat >> 6, kp = flat & 63;
      int ks = kp ^ ((r & 7) << 3);
      async16(gbase + (size_t)(h * 128 + r) * K + t * 64 + ks, lbase + flat);
    }
  };
  auto stA = [&](int c, int h, int t) { stage(Ag, Ab0 + (c * 2 + h) * 8192, h, t); };
  auto stB = [&](int c, int h, int t) { stage(Bg, Bb0 + (c * BH + h) * 8192, h, t); };

  const int xsw = (lr & 7) << 3;
  bf16x8 a_[8], b_[FN][2];
  auto lda = [&](int c, int kk) {
    const bf16_t* base = Ab0 + (c * 2 + wm) * 8192;
#pragma unroll
    for (int mf = 0; mf < 8; ++mf)
      a_[mf] = *(const bf16x8*)(base + (mf * 16 + lr) * 64 + ((kk + lg * 8) ^ xsw));
  };
  auto ldb = [&](int c) {
#pragma unroll
    for (int nf = 0; nf < FN; ++nf) {
      int row = wn * (FN * 16) + nf * 16 + lr;
      const bf16_t* base =
          Bb0 + (c * BH + (BH == 2 ? (row >> 7) : 0)) * 8192 + (row & 127) * 64;
#pragma unroll
      for (int kx = 0; kx < 2; ++kx)
        b_[nf][kx] = *(const bf16x8*)(base + ((kx * 32 + lg * 8) ^ xsw));
    }
  };

#define LGKM0 asm volatile("s_waitcnt lgkmcnt(0)" ::: "memory");
#define VMC_STEADY                                                   \
  if (BH == 2) { asm volatile("s_waitcnt vmcnt(6)" ::: "memory"); }  \
  else         { asm volatile("s_waitcnt vmcnt(4)" ::: "memory"); }
#define MFMA_HALF(M0, KX)                                            \
  __builtin_amdgcn_s_setprio(1);                                     \
  _Pragma("unroll")                                                  \
  for (int mf = 0; mf < 4; ++mf)                                     \
    _Pragma("unroll")                                                \
    for (int nf = 0; nf < FN; ++nf)                                  \
      acc[(M0) + mf][nf] = __builtin_amdgcn_mfma_f32_16x16x32_bf16(  \
          a_[(M0) + mf], b_[nf][KX], acc[(M0) + mf][nf], 0, 0, 0);   \
  __builtin_amdgcn_s_setprio(0);

  const int nit = K >> 7;  // 2 K-tiles (of 64) per iteration

  // ---- prologue: T0 all halves, then T1.{B0[,B1],A0} ----
  stA(0, 0, 0); stA(0, 1, 0);
  stB(0, 0, 0); if (BH == 2) stB(0, 1, 0);
  stB(1, 0, 1); if (BH == 2) stB(1, 1, 1);
  stA(1, 0, 1);
  VMC_STEADY;
  hard_barrier();

  for (int i = 0; i < nit; ++i) {
    const int t1 = 2 * i + 1, t2 = 2 * i + 2, t3 = 2 * i + 3;
    const bool g2 = (i < nit - 1);
    // ---- P1 ----
    lda(0, 0); ldb(0);
    stA(1, 1, t1);
    hard_barrier(); LGKM0;
    MFMA_HALF(0, 0)
    hard_barrier();
    // ---- P2 ----
    if (g2) stB(0, 0, t2);
    hard_barrier();
    MFMA_HALF(4, 0)
    hard_barrier();
    // ---- P3 ----
    lda(0, 32);
    if (g2 && BH == 2) stB(0, 1, t2);
    hard_barrier(); LGKM0;
    MFMA_HALF(0, 1)
    hard_barrier();
    // ---- P4 ----
    if (g2) stA(0, 0, t2);
    if (i == nit - 1) { asm volatile("s_waitcnt vmcnt(0)" ::: "memory"); }
    else { VMC_STEADY; }
    hard_barrier();
    MFMA_HALF(4, 1)
    hard_barrier();
    // ---- P5 ----
    lda(1, 0); ldb(1);
    if (g2) stA(0, 1, t2);
    hard_barrier(); LGKM0;
    MFMA_HALF(0, 0)
    hard_barrier();
    // ---- P6 ----
    if (g2) stB(1, 0, t3);
    hard_barrier();
    MFMA_HALF(4, 0)
    hard_barrier();
    // ---- P7 ----
    lda(1, 32);
    if (g2 && BH == 2) stB(1, 1, t3);
    hard_barrier(); LGKM0;
    MFMA_HALF(0, 1)
    hard_barrier();
    // ---- P8 ----
    if (g2) {
      stA(1, 0, t3);
      VMC_STEADY;
    }
    hard_barrier();
    MFMA_HALF(4, 1)
    hard_barrier();
  }
#undef LGKM0
#undef VMC_STEADY
#undef MFMA_HALF
}

// ---------------- generic 8-phase GEMM kernel ----------------
// EPI bits: 1 = exact GELU, 2 = add residual f32, 4 = write f32, 8 = write bf16
template <int FN, int EPI>
__global__ __launch_bounds__(512, 2)
void k_gemm8(const bf16_t* __restrict__ A, const bf16_t* __restrict__ BT,
             const float* __restrict__ bias, const float* __restrict__ res,
             float* __restrict__ outF, bf16_t* __restrict__ outB, int N, int K) {
  extern __shared__ __align__(16) bf16_t sh8[];
  constexpr int BN = FN * 64;
  int nt = N / BN;
  int bm = blockIdx.x / nt, bn = blockIdx.x % nt;
  f32x4 acc[8][FN] = {};
  gemm8_loop<FN>(A, BT, K, bm, bn, acc, sh8);
  int tid = threadIdx.x, wave = tid >> 6, lane = tid & 63, lr = lane & 15, lg = lane >> 4;
  int wm = wave >> 2, wn = wave & 3;
  int row0 = bm * 256 + wm * 128 + lg * 4;
  int col0 = bn * BN + wn * (FN * 16) + lr;
#pragma unroll
  for (int nf = 0; nf < FN; ++nf) {
    int c = col0 + nf * 16;
    float bi = bias[c];
#pragma unroll
    for (int mf = 0; mf < 8; ++mf) {
#pragma unroll
      for (int j = 0; j < 4; ++j) {
        int r = row0 + mf * 16 + j;
        size_t idx = (size_t)r * N + c;
        float v = acc[mf][nf][j] + bi;
        if (EPI & 1) v = gelu_f(v);
        if (EPI & 2) v += res[idx];
        if (EPI & 4) outF[idx] = v;
        if (EPI & 8) outB[idx] = (bf16_t)v;
      }
    }
  }
}

// ---------------- fused QKV 8-phase GEMM: N = 2304 (2048 q|128 k|128 v) ------
__global__ __launch_bounds__(512, 2)
void k_gemm8_qkv(const bf16_t* __restrict__ A, const bf16_t* __restrict__ BT,
                 const float* __restrict__ bq, const float* __restrict__ bk,
                 const float* __restrict__ bv,
                 bf16_t* __restrict__ qb, float* __restrict__ outk,
                 float* __restrict__ outv, bf16_t* __restrict__ kbf,
                 bf16_t* __restrict__ vbf, int K) {
  extern __shared__ __align__(16) bf16_t sh8[];
  const int nt = NQKV / 256;  // 9
  int bm = blockIdx.x / nt, bn = blockIdx.x % nt;
  f32x4 acc[8][4] = {};
  gemm8_loop<4>(A, BT, K, bm, bn, acc, sh8);
  int tid = threadIdx.x, wave = tid >> 6, lane = tid & 63, lr = lane & 15, lg = lane >> 4;
  int wm = wave >> 2, wn = wave & 3;
  int row0 = bm * 256 + wm * 128 + lg * 4;
  int col0 = bn * 256 + wn * 64 + lr;
#pragma unroll
  for (int nf = 0; nf < 4; ++nf) {
    int c = col0 + nf * 16;
    float bi = (c < 2048) ? bq[c] : (c < 2176 ? bk[c - 2048] : bv[c - 2176]);
#pragma unroll
    for (int mf = 0; mf < 8; ++mf) {
#pragma unroll
      for (int j = 0; j < 4; ++j) {
        int r = row0 + mf * 16 + j;
        float v = acc[mf][nf][j] + bi;
        if (c < 2048) {
          qb[(size_t)r * DIMSZ + c] = (bf16_t)v;
        } else if (c < 2176) {
          int cc = c - 2048;
          outk[(size_t)r * HD + cc] = v;
          kbf[(size_t)r * HD + cc] = (bf16_t)v;
        } else {
          int cc = c - 2176;
          outv[(size_t)r * HD + cc] = v;
          vbf[(size_t)r * HD + cc] = (bf16_t)v;
        }
      }
    }
  }
}

// ---------------- causal flash attention (MQA) ----------------
// Block = 4 waves sharing one 64-row q-tile (16 rows/wave). Block p handles
// q-tiles {p, 31-p} sequentially -> uniform 33 KV-tiles/block. K [64][128] and
// V^T [128][64] staged in LDS (double-buffered) via global_load_lds with
// chunk-XOR swizzle (pre-swizzled global source + XOR on ds_read). 2-phase
// pipeline: STAGE(t+1) issued before compute(t), one barrier per tile.
__global__ __launch_bounds__(256, 2)
void k_attn(const bf16_t* __restrict__ q, const bf16_t* __restrict__ k,
            const bf16_t* __restrict__ vt, bf16_t* __restrict__ ctx) {
  __shared__ __align__(16) bf16_t Ks[2][64 * 128];
  __shared__ __align__(16) bf16_t Vs[2][128 * 64];
  __shared__ bf16_t Pw[4][16][72];
  int pp = blockIdx.x, h = blockIdx.y, b = blockIdx.z;
  int tid = threadIdx.x, wave = tid >> 6, lane = tid & 63, lr = lane & 15, lg = lane >> 4;
  const bf16_t* kb = k + (size_t)b * SEQ * HD;
  const bf16_t* vb = vt + (size_t)b * HD * SEQ;

#define STAGE_TILE(buf, s0_)                                                      \
  {                                                                               \
    _Pragma("unroll")                                                             \
    for (int i = 0; i < 4; ++i) {                                                 \
      int flat = (i * 256 + tid) * 8;                                             \
      int kr = flat >> 7, kc = flat & 127;                                        \
      int ksrc = (((kc >> 3) ^ (kr & 7)) << 3) | (kc & 7);                        \
      async16(kb + (size_t)((s0_) + kr) * HD + ksrc, (void*)(Ks[buf] + flat));    \
      int vr = flat >> 6, vc = flat & 63;                                         \
      int vsrc = (((vc >> 3) ^ (vr & 7)) << 3) | (vc & 7);                        \
      async16(vb + (size_t)vr * SEQ + (s0_) + vsrc, (void*)(Vs[buf] + flat));     \
    }                                                                             \
  }

  for (int half = 0; half < 2; ++half) {
    int qt = half ? (31 - pp) : pp;
    int q0 = qt * 64;
    int qw = q0 + wave * 16;
    const bf16_t* qbase = q + ((size_t)(b * SEQ + qw + lr)) * DIMSZ + h * HD;
    bf16x8 qf[4];
#pragma unroll
    for (int kk = 0; kk < 4; ++kk) qf[kk] = *(const bf16x8*)(qbase + kk * 32 + lg * 8);
    f32x4 o[8] = {};
    float m_[4], l_[4];
#pragma unroll
    for (int j = 0; j < 4; ++j) { m_[j] = -3.0e38f; l_[j] = 0.f; }
    int qglob0 = qw + lg * 4;
    int ntiles = qt + 1;

    STAGE_TILE(0, 0)
    __syncthreads();
    for (int t = 0; t < ntiles; ++t) {
      int cur = t & 1;
      if (t + 1 < ntiles) STAGE_TILE(cur ^ 1, (t + 1) * 64)
      int s0 = t * 64;
      const bf16_t* Kc = Ks[cur];
      const bf16_t* Vc = Vs[cur];
      f32x4 sf[4] = {};
#pragma unroll
      for (int nf = 0; nf < 4; ++nf) {
        int R = nf * 16 + lr;
#pragma unroll
        for (int kk = 0; kk < 4; ++kk)
          sf[nf] = __builtin_amdgcn_mfma_f32_16x16x32_bf16(
              qf[kk],
              *(const bf16x8*)(Kc + R * 128 + (((kk * 4 + lg) ^ (R & 7)) << 3)),
              sf[nf], 0, 0, 0);
      }
#pragma unroll
      for (int nf = 0; nf < 4; ++nf) {
        int col = s0 + nf * 16 + lr;
#pragma unroll
        for (int j = 0; j < 4; ++j) {
          float v = sf[nf][j] * 0.088388347648318447f;
          sf[nf][j] = (col <= qglob0 + j) ? v : -3.0e38f;
        }
      }
      float mx[4];
#pragma unroll
      for (int j = 0; j < 4; ++j)
        mx[j] = fmaxf(fmaxf(sf[0][j], sf[1][j]), fmaxf(sf[2][j], sf[3][j]));
#pragma unroll
      for (int o_ = 1; o_ < 16; o_ <<= 1)
#pragma unroll
        for (int j = 0; j < 4; ++j) mx[j] = fmaxf(mx[j], __shfl_xor(mx[j], o_));
      float fsc[4], mn[4];
#pragma unroll
      for (int j = 0; j < 4; ++j) {
        mn[j] = fmaxf(m_[j], mx[j]);
        fsc[j] = __expf(m_[j] - mn[j]);
        m_[j] = mn[j];
      }
      float ps[4] = {0.f, 0.f, 0.f, 0.f};
#pragma unroll
      for (int nf = 0; nf < 4; ++nf)
#pragma unroll
        for (int j = 0; j < 4; ++j) {
          float pv = __expf(sf[nf][j] - mn[j]);
          ps[j] += pv;
          Pw[wave][lg * 4 + j][nf * 16 + lr] = (bf16_t)pv;
        }
#pragma unroll
      for (int o_ = 1; o_ < 16; o_ <<= 1)
#pragma unroll
        for (int j = 0; j < 4; ++j) ps[j] += __shfl_xor(ps[j], o_);
#pragma unroll
      for (int j = 0; j < 4; ++j) l_[j] = l_[j] * fsc[j] + ps[j];
#pragma unroll
      for (int df = 0; df < 8; ++df)
#pragma unroll
        for (int j = 0; j < 4; ++j) o[df][j] *= fsc[j];
      asm volatile("" ::: "memory");
      bf16x8 pa[2];
#pragma unroll
      for (int kk = 0; kk < 2; ++kk)
        pa[kk] = *(const bf16x8*)(&Pw[wave][lr][kk * 32 + lg * 8]);
#pragma unroll
      for (int df = 0; df < 8; ++df) {
        int R = df * 16 + lr;
#pragma unroll
        for (int kk = 0; kk < 2; ++kk)
          o[df] = __builtin_amdgcn_mfma_f32_16x16x32_bf16(
              pa[kk],
              *(const bf16x8*)(Vc + R * 64 + (((kk * 4 + lg) ^ (R & 7)) << 3)),
              o[df], 0, 0, 0);
      }
      __syncthreads();
    }
    bf16_t* cb = ctx + ((size_t)(b * SEQ + qw)) * DIMSZ + h * HD;
#pragma unroll
    for (int df = 0; df < 8; ++df)
#pragma unroll
      for (int j = 0; j < 4; ++j)
        cb[(size_t)(lg * 4 + j) * DIMSZ + df * 16 + lr] = (bf16_t)(o[df][j] / l_[j]);
  }
#undef STAGE_TILE
}

extern "C" void kernel_launch(void* const* d_in, const int* in_sizes, int n_in,
                              void* d_out, int out_size, void* d_ws, size_t ws_size,
                              hipStream_t stream) {
  const float* x   = (const float*)d_in[0];
  const float* wq  = (const float*)d_in[2];
  const float* bq  = (const float*)d_in[3];
  const float* wk  = (const float*)d_in[4];
  const float* bk  = (const float*)d_in[5];
  const float* wv  = (const float*)d_in[6];
  const float* bv  = (const float*)d_in[7];
  const float* wo  = (const float*)d_in[8];
  const float* bo  = (const float*)d_in[9];
  const float* g1  = (const float*)d_in[10];
  const float* be1 = (const float*)d_in[11];
  const float* g2  = (const float*)d_in[12];
  const float* be2 = (const float*)d_in[13];
  const float* w1  = (const float*)d_in[14];
  const float* bb1 = (const float*)d_in[15];
  const float* w2  = (const float*)d_in[16];
  const float* bb2 = (const float*)d_in[17];

  float* outx = (float*)d_out;                       // [4096][2048] (also x1 scratch)
  float* outk = outx + (size_t)MROWS * DIMSZ;        // [4096][128]
  float* outv = outk + (size_t)MROWS * HD;           // [4096][128]

  char* p = (char*)d_ws;
  auto alloc = [&](size_t bytes) -> char* {
    char* r = p;
    p += (bytes + 255) & ~(size_t)255;
    return r;
  };
  bf16_t* wqkvT = (bf16_t*)alloc((size_t)NQKV * DIMSZ * 2);   // [2304][2048]
  bf16_t* woT = (bf16_t*)alloc((size_t)DIMSZ * DIMSZ * 2);
  bf16_t* w1T = (bf16_t*)alloc((size_t)FFDIM * DIMSZ * 2);
  bf16_t* w2T = (bf16_t*)alloc((size_t)DIMSZ * FFDIM * 2);
  bf16_t* hb  = (bf16_t*)alloc((size_t)MROWS * DIMSZ * 2);  // h, later ctx
  bf16_t* qb  = (bf16_t*)alloc((size_t)MROWS * DIMSZ * 2);  // q, later h2
  bf16_t* kbf = (bf16_t*)alloc((size_t)MROWS * HD * 2);
  bf16_t* vbf = (bf16_t*)alloc((size_t)MROWS * HD * 2);
  bf16_t* vtb = (bf16_t*)alloc((size_t)BATCH * HD * SEQ * 2);
  bf16_t* f1b = (bf16_t*)alloc((size_t)MROWS * FFDIM * 2);
  (void)ws_size; (void)in_sizes; (void)n_in; (void)out_size;

  dim3 blk(256);
  const int LDS4 = 131072;  // FN=4 (BN=256): A 64KB + B 64KB
  const int LDS2 = 98304;   // FN=2 (BN=128): A 64KB + B 32KB
  // weight transposes / bf16 conversion; wq/wk/wv land in one [2304][2048]
  k_transpose_f32_bf16<<<dim3(DIMSZ / 32, DIMSZ / 32), blk, 0, stream>>>(wq, wqkvT, DIMSZ, DIMSZ);
  k_transpose_f32_bf16<<<dim3(HD / 32, DIMSZ / 32), blk, 0, stream>>>(wk, wqkvT + (size_t)2048 * DIMSZ, DIMSZ, HD);
  k_transpose_f32_bf16<<<dim3(HD / 32, DIMSZ / 32), blk, 0, stream>>>(wv, wqkvT + (size_t)2176 * DIMSZ, DIMSZ, HD);
  k_transpose_f32_bf16<<<dim3(DIMSZ / 32, DIMSZ / 32), blk, 0, stream>>>(wo, woT, DIMSZ, DIMSZ);
  k_transpose_f32_bf16<<<dim3(FFDIM / 32, DIMSZ / 32), blk, 0, stream>>>(w1, w1T, DIMSZ, FFDIM);
  k_transpose_f32_bf16<<<dim3(DIMSZ / 32, FFDIM / 32), blk, 0, stream>>>(w2, w2T, FFDIM, DIMSZ);
  // ln1: x -> h(bf16)
  k_layernorm<<<MROWS, blk, 0, stream>>>(x, g1, be1, hb);
  // fused q,k,v projection (N=2304, 16x9 = 144 blocks)
  k_gemm8_qkv<<<(MROWS / 256) * (NQKV / 256), 512, LDS4, stream>>>(
      hb, wqkvT, bq, bk, bv, qb, outk, outv, kbf, vbf, DIMSZ);
  k_transpose_v<<<dim3(SEQ / 32, HD / 32, BATCH), blk, 0, stream>>>(vbf, vtb);
  // attention -> ctx (reuse hb)
  k_attn<<<dim3(SEQ / 64 / 2, NH, BATCH), blk, 0, stream>>>(qb, kbf, vtb, hb);
  // o-proj + residual -> outx (x1): BN=128 -> 16x16 = 256 blocks
  k_gemm8<2, 6><<<(MROWS / 256) * (DIMSZ / 128), 512, LDS2, stream>>>(
      hb, woT, bo, x, outx, nullptr, DIMSZ, DIMSZ);
  // ln2: x1 -> h2 (reuse qb)
  k_layernorm<<<MROWS, blk, 0, stream>>>(outx, g2, be2, qb);
  // ffn1 + exact gelu -> f1b (bf16): BN=256 -> 16x32 = 512 blocks
  k_gemm8<4, 9><<<(MROWS / 256) * (FFDIM / 256), 512, LDS4, stream>>>(
      qb, w1T, bb1, nullptr, nullptr, f1b, FFDIM, DIMSZ);
  // ffn2 + residual -> outx (final x): BN=128, K=8192 -> 256 blocks
  k_gemm8<2, 6><<<(MROWS / 256) * (DIMSZ / 128), 512, LDS2, stream>>>(
      f1b, w2T, bb2, outx, outx, nullptr, DIMSZ, FFDIM);
}